// Round 1
// baseline (353.738 us; speedup 1.0000x reference)
//
#include <hip/hip_runtime.h>

#define Cc 64
#define Dd 128
#define Nn 32
#define Kk 4
#define Rr 4
#define Bb 2
#define Hh 48
#define Ww 48
#define Ll 2304
#define EPSf 1e-5f
#define LCc 288   // scan chunk length = L/8

__device__ __forceinline__ float wsum64(float v) {
  v += __shfl_xor(v, 32);
  v += __shfl_xor(v, 16);
  v += __shfl_xor(v, 8);
  v += __shfl_xor(v, 4);
  v += __shfl_xor(v, 2);
  v += __shfl_xor(v, 1);
  return v;
}

// ---------------- K1: pre-LN (over C) + in_proj (C -> 2D), split x/z ----------------
// block=256 (4 waves), 16 pixels/block (4 per wave). xin stored (B,D,L) via LDS
// transpose for coalesced stores; z stored (B,L,D) directly (coalesced).
__global__ __launch_bounds__(256) void k1_ln_inproj(
    const float* __restrict__ x, const float* __restrict__ g,
    const float* __restrict__ bta, const float* __restrict__ Wp,
    float* __restrict__ xin, float* __restrict__ zb)
{
  __shared__ float xnS[16][64];
  __shared__ float xaS[128][17];
  const int tid = threadIdx.x;
  const int wv = tid >> 6, lane = tid & 63;
  const int pbase = blockIdx.x * 16;       // 4608 pixels total, no b-straddle
  const int b = pbase / Ll;
  const int lbase = pbase % Ll;
  const float gv = g[lane], bv = bta[lane];
  for (int pi = 0; pi < 4; ++pi) {
    const int l = lbase + wv * 4 + pi;
    float v = x[(b * Cc + lane) * Ll + l];
    float mu = wsum64(v) * (1.0f / 64.0f);
    float dv = v - mu;
    float var = wsum64(dv * dv) * (1.0f / 64.0f);
    float rs = rsqrtf(var + EPSf);
    xnS[wv * 4 + pi][lane] = dv * rs * gv + bv;
  }
  __syncthreads();
  float acc[4][4];
  #pragma unroll
  for (int pi = 0; pi < 4; ++pi)
    #pragma unroll
    for (int m = 0; m < 4; ++m) acc[pi][m] = 0.f;
  const float4* W4 = (const float4*)Wp;
  #pragma unroll 4
  for (int c4 = 0; c4 < 16; ++c4) {
    float4 xn4[4];
    #pragma unroll
    for (int pi = 0; pi < 4; ++pi)
      xn4[pi] = ((const float4*)xnS[wv * 4 + pi])[c4];
    #pragma unroll
    for (int m = 0; m < 4; ++m) {
      const float4 w4 = W4[(lane + 64 * m) * 16 + c4];
      #pragma unroll
      for (int pi = 0; pi < 4; ++pi)
        acc[pi][m] += xn4[pi].x * w4.x + xn4[pi].y * w4.y +
                      xn4[pi].z * w4.z + xn4[pi].w * w4.w;
    }
  }
  #pragma unroll
  for (int pi = 0; pi < 4; ++pi) {
    const int l = lbase + wv * 4 + pi;
    zb[(b * Ll + l) * Dd + lane]      = acc[pi][2];   // j in [128,192)
    zb[(b * Ll + l) * Dd + lane + 64] = acc[pi][3];   // j in [192,256)
    xaS[lane][wv * 4 + pi]      = acc[pi][0];         // j in [0,64)
    xaS[lane + 64][wv * 4 + pi] = acc[pi][1];         // j in [64,128)
  }
  __syncthreads();
  const int d = tid >> 1, off = (tid & 1) * 8;
  float* dst = &xin[(b * Dd + d) * Ll + lbase + off];
  #pragma unroll
  for (int i = 0; i < 8; ++i) dst[i] = xaS[d][off + i];
}

// ---------------- K2: depthwise 3x3 conv (SAME) + bias + SiLU ----------------
__global__ __launch_bounds__(256) void k2_conv(
    const float* __restrict__ xin, const float* __restrict__ cw,
    const float* __restrict__ cb, float* __restrict__ xc)
{
  const int idx = blockIdx.x * 256 + threadIdx.x;   // exactly B*D*L threads
  const int l = idx % Ll;
  const int bd = idx / Ll;
  const int d = bd % Dd;
  const int h = l / Ww, w = l % Ww;
  float acc = cb[d];
  #pragma unroll
  for (int i = 0; i < 3; ++i) {
    const int hh = h + i - 1;
    if (hh < 0 || hh >= Hh) continue;
    #pragma unroll
    for (int j = 0; j < 3; ++j) {
      const int ww2 = w + j - 1;
      if (ww2 < 0 || ww2 >= Ww) continue;
      acc += xin[bd * Ll + hh * Ww + ww2] * cw[d * 9 + i * 3 + j];
    }
  }
  const float sig = 1.0f / (1.0f + __expf(-acc));
  xc[idx] = acc * sig;
}

// ---------------- K3: per-pixel x_dbl projection + dt proj + softplus ----------------
// block=320, 8 pixels/block so x_proj_w rows are reused 8x per global read.
__global__ __launch_bounds__(320) void k3_proj(
    const float* __restrict__ xc, const float* __restrict__ xpw,
    const float* __restrict__ dtw, const float* __restrict__ dtb,
    float* __restrict__ deltaB, float* __restrict__ Bm, float* __restrict__ Cm)
{
  __shared__ float xvS[8][128];
  __shared__ float dtsS[8][16];
  const int t = threadIdx.x;
  const int pb = blockIdx.x * 8;
  const int b = pb / Ll;
  const int lb = pb % Ll;
  for (int i = t; i < 1024; i += 320) {
    const int pi = i >> 7, d = i & 127;
    xvS[pi][d] = xc[(b * Dd + d) * Ll + lb + pi];
  }
  __syncthreads();
  if (t < 272) {
    const int k = t / 68, c = t % 68;
    float acc[8];
    #pragma unroll
    for (int pi = 0; pi < 8; ++pi) acc[pi] = 0.f;
    const float4* w4p = (const float4*)(xpw + (k * 68 + c) * 128);
    for (int d4 = 0; d4 < 32; ++d4) {
      const float4 w4 = w4p[d4];
      #pragma unroll
      for (int pi = 0; pi < 8; ++pi) {
        const float4 x4 = ((const float4*)xvS[pi])[d4];
        acc[pi] += x4.x * w4.x + x4.y * w4.y + x4.z * w4.z + x4.w * w4.w;
      }
    }
    #pragma unroll
    for (int pi = 0; pi < 8; ++pi) {
      const int l0 = lb + pi;
      const int h = l0 / Ww, w = l0 % Ww;
      int lk;
      if      (k == 0) lk = l0;
      else if (k == 1) lk = w * Hh + h;
      else if (k == 2) lk = Ll - 1 - l0;
      else             lk = Ll - 1 - (w * Hh + h);
      if (c < Rr)            dtsS[pi][k * 4 + c] = acc[pi];
      else if (c < Rr + Nn)  Bm[((b * Kk + k) * Ll + lk) * Nn + (c - Rr)] = acc[pi];
      else                   Cm[((b * Kk + k) * Ll + lk) * Nn + (c - Rr - Nn)] = acc[pi];
    }
  }
  __syncthreads();
  for (int i = t; i < 4096; i += 320) {   // 8 pixels x K x D delta outputs
    const int pi = i >> 9;
    const int rem = i & 511;
    const int k = rem >> 7, dd = rem & 127;
    const float4 dw = *(const float4*)(dtw + (k * 128 + dd) * 4);
    float a = dtb[k * 128 + dd]
            + dtsS[pi][k * 4 + 0] * dw.x + dtsS[pi][k * 4 + 1] * dw.y
            + dtsS[pi][k * 4 + 2] * dw.z + dtsS[pi][k * 4 + 3] * dw.w;
    const float sp = (a > 20.f) ? a : log1pf(__expf(a));
    const int l0 = lb + pi;
    const int h = l0 / Ww, w = l0 % Ww;
    int lk;
    if      (k == 0) lk = l0;
    else if (k == 1) lk = w * Hh + h;
    else if (k == 2) lk = Ll - 1 - l0;
    else             lk = Ll - 1 - (w * Hh + h);
    deltaB[((b * Kk + k) * Ll + lk) * Dd + dd] = sp;
  }
}

// ---------------- K4: chunked two-pass selective scan ----------------
// block=512: 2 channels x 8 chunks x 32 lanes(n). Phase A: local h_end + sum(delta).
// In-block serial carry combine (decay over chunk = exp(A*sumDelta)). Phase B: rerun
// chunks with correct carry, emit y via 32-lane shuffle reduce.
__device__ __forceinline__ int mapk(int k, int l) {
  int tpos = (k & 2) ? (Ll - 1 - l) : l;
  if (k & 1) tpos = (tpos % 48) * 48 + (tpos / 48);
  return tpos;
}

__global__ __launch_bounds__(512) void k4_scan(
    const float* __restrict__ xc, const float* __restrict__ deltaB,
    const float* __restrict__ BmB, const float* __restrict__ CmB,
    const float* __restrict__ Alogs, const float* __restrict__ DsP,
    float* __restrict__ ys)
{
  __shared__ float hendS[16][32];
  __shared__ float carryS[16][32];
  __shared__ float sumDS[16];
  const int tid = threadIdx.x;
  const int g = tid >> 5, n = tid & 31;
  const int ch = g & 1, s = g >> 1;
  const int blk = blockIdx.x;          // (b,k,dpair): 2*4*64 = 512
  const int dpair = blk & 63;
  const int k = (blk >> 6) & 3;
  const int b = blk >> 8;
  const int d = dpair * 2 + ch;
  const float An = -__expf(Alogs[(k * Dd + d) * Nn + n]);
  const float* dP = deltaB + (size_t)((b * Kk + k) * Ll) * Dd + d;
  const float* BP = BmB + (size_t)((b * Kk + k) * Ll) * Nn + n;
  const float* CP = CmB + (size_t)((b * Kk + k) * Ll) * Nn + n;
  const float* uP = xc + (size_t)(b * Dd + d) * Ll;
  const int lbeg = s * LCc;
  // phase A: local scan (h_end) + sum of deltas
  float hA = 0.f, sumD = 0.f;
  for (int l = lbeg; l < lbeg + LCc; ++l) {
    const float delta = dP[(size_t)l * Dd];
    const float u = uP[mapk(k, l)];
    const float Bn = BP[(size_t)l * Nn];
    const float dA = __expf(delta * An);
    hA = dA * hA + (delta * u) * Bn;
    sumD += delta;
  }
  hendS[g][n] = hA;
  if (n == 0) sumDS[g] = sumD;
  __syncthreads();
  // serial carry combine across the 8 chunks (one wave)
  if (tid < 64) {
    const int ch2 = tid >> 5, n2 = tid & 31;
    const int d2 = dpair * 2 + ch2;
    const float A2 = -__expf(Alogs[(k * Dd + d2) * Nn + n2]);
    float carry = 0.f;
    #pragma unroll
    for (int s2 = 0; s2 < 8; ++s2) {
      const int g2 = (s2 << 1) | ch2;
      carryS[g2][n2] = carry;
      carry = __expf(A2 * sumDS[g2]) * carry + hendS[g2][n2];
    }
  }
  __syncthreads();
  // phase B: rerun with correct carry-in, emit y
  float h = carryS[g][n];
  const float Dval = DsP[k * Dd + d];
  float* yP = ys + (size_t)((b * Kk + k) * Ll) * Dd + d;
  for (int l = lbeg; l < lbeg + LCc; ++l) {
    const float delta = dP[(size_t)l * Dd];
    const float u = uP[mapk(k, l)];
    const float Bn = BP[(size_t)l * Nn];
    const float Cn = CP[(size_t)l * Nn];
    const float dA = __expf(delta * An);
    h = dA * h + (delta * u) * Bn;
    float pv = h * Cn;
    pv += __shfl_xor(pv, 16);
    pv += __shfl_xor(pv, 8);
    pv += __shfl_xor(pv, 4);
    pv += __shfl_xor(pv, 2);
    pv += __shfl_xor(pv, 1);
    if (n == 0) yP[(size_t)l * Dd] = pv + Dval * u;   // lanes 0 & 32 -> 8B store
  }
}

// ---------------- K5: 4-direction merge + out-LN + SiLU(z)* + out_proj + residual ----------------
__global__ __launch_bounds__(256) void k5_merge(
    const float* __restrict__ ys, const float* __restrict__ zb,
    const float* __restrict__ og, const float* __restrict__ ob,
    const float* __restrict__ Wo, const float* __restrict__ resid,
    float* __restrict__ out)
{
  __shared__ float tS[16][128];
  __shared__ float oS[64][17];
  const int tid = threadIdx.x;
  const int wv = tid >> 6, lane = tid & 63;
  const int pbase = blockIdx.x * 16;
  const int b = pbase / Ll;
  const int lbase = pbase % Ll;
  for (int pi = 0; pi < 4; ++pi) {
    const int l0 = lbase + wv * 4 + pi;
    const int h = l0 / Ww, w = l0 % Ww;
    const int l1 = w * Hh + h;
    const size_t base = (size_t)(b * Kk) * Ll * Dd;
    float tv[2];
    #pragma unroll
    for (int m = 0; m < 2; ++m) {
      const int dch = lane + 64 * m;
      tv[m] = ys[base + (size_t)l0 * Dd + dch]
            + ys[base + ((size_t)Ll + l1) * Dd + dch]
            + ys[base + ((size_t)2 * Ll + (Ll - 1 - l0)) * Dd + dch]
            + ys[base + ((size_t)3 * Ll + (Ll - 1 - l1)) * Dd + dch];
    }
    const float mu = wsum64(tv[0] + tv[1]) * (1.0f / 128.0f);
    const float q = wsum64((tv[0] - mu) * (tv[0] - mu) +
                           (tv[1] - mu) * (tv[1] - mu)) * (1.0f / 128.0f);
    const float rs = rsqrtf(q + EPSf);
    #pragma unroll
    for (int m = 0; m < 2; ++m) {
      const int dch = lane + 64 * m;
      const float zz = zb[(size_t)(b * Ll + l0) * Dd + dch];
      const float sig = 1.0f / (1.0f + __expf(-zz));
      tS[wv * 4 + pi][dch] = ((tv[m] - mu) * rs * og[dch] + ob[dch]) * (zz * sig);
    }
  }
  __syncthreads();
  float acc[4] = {0.f, 0.f, 0.f, 0.f};
  const float4* W4 = (const float4*)Wo;     // out_proj_w (64,128)
  for (int d4 = 0; d4 < 32; ++d4) {
    const float4 w4 = W4[lane * 32 + d4];
    #pragma unroll
    for (int pi = 0; pi < 4; ++pi) {
      const float4 t4 = ((const float4*)tS[wv * 4 + pi])[d4];
      acc[pi] += t4.x * w4.x + t4.y * w4.y + t4.z * w4.z + t4.w * w4.w;
    }
  }
  #pragma unroll
  for (int pi = 0; pi < 4; ++pi) oS[lane][wv * 4 + pi] = acc[pi];
  __syncthreads();
  const int c = tid >> 2, off = (tid & 3) * 4;
  const size_t obase = (size_t)(b * Cc + c) * Ll + lbase + off;
  const float4 r4 = *(const float4*)(resid + obase);
  float4 o4;
  o4.x = oS[c][off + 0] + r4.x;
  o4.y = oS[c][off + 1] + r4.y;
  o4.z = oS[c][off + 2] + r4.z;
  o4.w = oS[c][off + 3] + r4.w;
  *(float4*)(out + obase) = o4;
}

extern "C" void kernel_launch(void* const* d_in, const int* in_sizes, int n_in,
                              void* d_out, int out_size, void* d_ws, size_t ws_size,
                              hipStream_t stream)
{
  (void)in_sizes; (void)n_in; (void)out_size; (void)ws_size;
  const float* fufea1     = (const float*)d_in[0];
  const float* ln_g       = (const float*)d_in[1];
  const float* ln_b       = (const float*)d_in[2];
  const float* in_proj_w  = (const float*)d_in[3];
  const float* conv_w     = (const float*)d_in[4];
  const float* conv_b     = (const float*)d_in[5];
  const float* x_proj_w   = (const float*)d_in[6];
  const float* dt_w       = (const float*)d_in[7];
  const float* dt_b       = (const float*)d_in[8];
  const float* A_logs     = (const float*)d_in[9];
  const float* Ds         = (const float*)d_in[10];
  const float* out_ln_g   = (const float*)d_in[11];
  const float* out_ln_b   = (const float*)d_in[12];
  const float* out_proj_w = (const float*)d_in[13];

  float* ws     = (float*)d_ws;
  float* xin    = ws;               // (B,D,L)   589824
  float* zb     = ws + 589824;      // (B,L,D)   589824
  float* xc     = ws + 1179648;     // (B,D,L)   589824
  float* deltaB = ws + 1769472;     // (B,K,L,D) 2359296
  float* Bm     = ws + 4128768;     // (B,K,L,N) 589824
  float* Cm     = ws + 4718592;     // (B,K,L,N) 589824
  float* ysb    = ws + 5308416;     // (B,K,L,D) 2359296  (end: 7667712 floats ~30.7MB)

  k1_ln_inproj<<<288, 256, 0, stream>>>(fufea1, ln_g, ln_b, in_proj_w, xin, zb);
  k2_conv<<<2304, 256, 0, stream>>>(xin, conv_w, conv_b, xc);
  k3_proj<<<576, 320, 0, stream>>>(xc, x_proj_w, dt_w, dt_b, deltaB, Bm, Cm);
  k4_scan<<<512, 512, 0, stream>>>(xc, deltaB, Bm, Cm, A_logs, Ds, ysb);
  k5_merge<<<288, 256, 0, stream>>>(ysb, zb, out_ln_g, out_ln_b, out_proj_w, fufea1,
                                    (float*)d_out);
}

// Round 2
// 269.937 us; speedup vs baseline: 1.3104x; 1.3104x over previous
//
#include <hip/hip_runtime.h>

#define Cc 64
#define Dd 128
#define Nn 32
#define Kk 4
#define Rr 4
#define Bb 2
#define Hh 48
#define Ww 48
#define Ll 2304
#define EPSf 1e-5f
#define LCc 144   // scan chunk length = L/16

#if __has_builtin(__builtin_amdgcn_exp2f)
#define EXP2F __builtin_amdgcn_exp2f
#else
#define EXP2F exp2f
#endif

__device__ __forceinline__ float wsum64(float v) {
  v += __shfl_xor(v, 32);
  v += __shfl_xor(v, 16);
  v += __shfl_xor(v, 8);
  v += __shfl_xor(v, 4);
  v += __shfl_xor(v, 2);
  v += __shfl_xor(v, 1);
  return v;
}

// ---------------- K1: pre-LN (over C) + in_proj (C -> 2D), split x/z ----------------
__global__ __launch_bounds__(256) void k1_ln_inproj(
    const float* __restrict__ x, const float* __restrict__ g,
    const float* __restrict__ bta, const float* __restrict__ Wp,
    float* __restrict__ xin, float* __restrict__ zb)
{
  __shared__ float xS[16][65];
  __shared__ float xnS[16][64];
  __shared__ float xaS[128][17];
  const int tid = threadIdx.x;
  const int wv = tid >> 6, lane = tid & 63;
  const int pbase = blockIdx.x * 16;       // 4608 pixels total, no b-straddle
  const int b = pbase / Ll;
  const int lbase = pbase % Ll;
  {  // coalesced staging: thread -> (c, 4 consecutive l)
    const int c = tid >> 2, li0 = (tid & 3) * 4;
    const float4 v4 = *(const float4*)&x[(b * Cc + c) * Ll + lbase + li0];
    xS[li0 + 0][c] = v4.x;
    xS[li0 + 1][c] = v4.y;
    xS[li0 + 2][c] = v4.z;
    xS[li0 + 3][c] = v4.w;
  }
  __syncthreads();
  const float gv = g[lane], bv = bta[lane];
  for (int pi = 0; pi < 4; ++pi) {
    const int p = wv * 4 + pi;
    const float v = xS[p][lane];
    const float mu = wsum64(v) * (1.0f / 64.0f);
    const float dv = v - mu;
    const float var = wsum64(dv * dv) * (1.0f / 64.0f);
    const float rs = rsqrtf(var + EPSf);
    xnS[p][lane] = dv * rs * gv + bv;
  }
  __syncthreads();
  float acc[4][4];
  #pragma unroll
  for (int pi = 0; pi < 4; ++pi)
    #pragma unroll
    for (int m = 0; m < 4; ++m) acc[pi][m] = 0.f;
  const float4* W4 = (const float4*)Wp;
  #pragma unroll 4
  for (int c4 = 0; c4 < 16; ++c4) {
    float4 xn4[4];
    #pragma unroll
    for (int pi = 0; pi < 4; ++pi)
      xn4[pi] = ((const float4*)xnS[wv * 4 + pi])[c4];
    #pragma unroll
    for (int m = 0; m < 4; ++m) {
      const float4 w4 = W4[(lane + 64 * m) * 16 + c4];
      #pragma unroll
      for (int pi = 0; pi < 4; ++pi)
        acc[pi][m] += xn4[pi].x * w4.x + xn4[pi].y * w4.y +
                      xn4[pi].z * w4.z + xn4[pi].w * w4.w;
    }
  }
  #pragma unroll
  for (int pi = 0; pi < 4; ++pi) {
    const int l = lbase + wv * 4 + pi;
    zb[(b * Ll + l) * Dd + lane]      = acc[pi][2];
    zb[(b * Ll + l) * Dd + lane + 64] = acc[pi][3];
    xaS[lane][wv * 4 + pi]      = acc[pi][0];
    xaS[lane + 64][wv * 4 + pi] = acc[pi][1];
  }
  __syncthreads();
  const int d = tid >> 1, off = (tid & 1) * 8;
  float* dst = &xin[(b * Dd + d) * Ll + lbase + off];
  #pragma unroll
  for (int i = 0; i < 8; ++i) dst[i] = xaS[d][off + i];
}

// ---------------- K2: depthwise 3x3 conv (SAME) + bias + SiLU ----------------
__global__ __launch_bounds__(256) void k2_conv(
    const float* __restrict__ xin, const float* __restrict__ cw,
    const float* __restrict__ cb, float* __restrict__ xc)
{
  const int idx = blockIdx.x * 256 + threadIdx.x;   // exactly B*D*L threads
  const int l = idx % Ll;
  const int bd = idx / Ll;
  const int d = bd % Dd;
  const int h = l / Ww, w = l % Ww;
  float acc = cb[d];
  #pragma unroll
  for (int i = 0; i < 3; ++i) {
    const int hh = h + i - 1;
    if (hh < 0 || hh >= Hh) continue;
    #pragma unroll
    for (int j = 0; j < 3; ++j) {
      const int ww2 = w + j - 1;
      if (ww2 < 0 || ww2 >= Ww) continue;
      acc += xin[bd * Ll + hh * Ww + ww2] * cw[d * 9 + i * 3 + j];
    }
  }
  const float sig = 1.0f / (1.0f + __expf(-acc));
  xc[idx] = acc * sig;
}

// ---------------- K3: projections; emits {delta, delta*u} stream + {B,C} pairs ----------------
__global__ __launch_bounds__(512) void k3_proj(
    const float* __restrict__ xc, const float* __restrict__ xpw,
    const float* __restrict__ dtw, const float* __restrict__ dtb,
    float2* __restrict__ dd2, float2* __restrict__ BC)
{
  __shared__ float xvS[8][132];
  __shared__ float dtsS[8][16];
  const int t = threadIdx.x;
  const int pb = blockIdx.x * 8;
  const int b = pb / Ll;
  const int lb = pb % Ll;
  {  // stage 8 pixels x 128 d
    const int d = t >> 2;
    const int li0 = (t & 3) * 2;
    const float2 v2 = *(const float2*)&xc[(b * Dd + d) * Ll + lb + li0];
    xvS[li0][d]     = v2.x;
    xvS[li0 + 1][d] = v2.y;
  }
  __syncthreads();
  if (t < 272) {
    const int k = t / 68, c = t % 68;
    const size_t bkL = (size_t)(b * Kk + k) * Ll;
    float acc[8];
    #pragma unroll
    for (int pi = 0; pi < 8; ++pi) acc[pi] = 0.f;
    const float4* w4p = (const float4*)(xpw + (k * 68 + c) * 128);
    for (int d4 = 0; d4 < 32; ++d4) {
      const float4 w4 = w4p[d4];
      #pragma unroll
      for (int pi = 0; pi < 8; ++pi) {
        const float4 x4 = ((const float4*)xvS[pi])[d4];
        acc[pi] += x4.x * w4.x + x4.y * w4.y + x4.z * w4.z + x4.w * w4.w;
      }
    }
    #pragma unroll
    for (int pi = 0; pi < 8; ++pi) {
      const int l0 = lb + pi;
      const int h = l0 / Ww, w = l0 % Ww;
      int lk;
      if      (k == 0) lk = l0;
      else if (k == 1) lk = w * Hh + h;
      else if (k == 2) lk = Ll - 1 - l0;
      else             lk = Ll - 1 - (w * Hh + h);
      if (c < Rr)            dtsS[pi][k * 4 + c] = acc[pi];
      else if (c < Rr + Nn)  BC[(bkL + lk) * Nn + (c - Rr)].x = acc[pi];
      else                   BC[(bkL + lk) * Nn + (c - Rr - Nn)].y = acc[pi];
    }
  }
  __syncthreads();
  {  // delta + softplus + pack {delta, delta*u}
    const int k = t >> 7, dd = t & 127;
    const float4 dw = *(const float4*)&dtw[(k * Dd + dd) * 4];
    const float biasv = dtb[k * Dd + dd];
    float2* drow = dd2 + ((size_t)((b * Kk + k) * Dd) + dd) * Ll;
    #pragma unroll
    for (int pi = 0; pi < 8; ++pi) {
      const float a = biasv
          + dtsS[pi][k * 4 + 0] * dw.x + dtsS[pi][k * 4 + 1] * dw.y
          + dtsS[pi][k * 4 + 2] * dw.z + dtsS[pi][k * 4 + 3] * dw.w;
      const float sp = (a > 20.f) ? a : log1pf(__expf(a));
      const int l0 = lb + pi;
      const int h = l0 / Ww, w = l0 % Ww;
      int lk;
      if      (k == 0) lk = l0;
      else if (k == 1) lk = w * Hh + h;
      else if (k == 2) lk = Ll - 1 - l0;
      else             lk = Ll - 1 - (w * Hh + h);
      drow[lk] = make_float2(sp, sp * xvS[pi][dd]);
    }
  }
}

// ---------------- K4: chunked two-pass selective scan, S=16 ----------------
// block = (b,k,d): 1024 blocks x 512 threads (16 chunks x 32 state-lanes).
__global__ __launch_bounds__(512) void k4_scan(
    const float2* __restrict__ dd2, const float2* __restrict__ BC,
    const float* __restrict__ Alogs, float* __restrict__ ys)
{
  __shared__ float hendS[16][32];
  __shared__ float carryS[16][32];
  __shared__ float sumDS[16];
  const int tid = threadIdx.x;
  const int s = tid >> 5, n = tid & 31;
  const int blk = blockIdx.x;
  const int d = blk & 127;
  const int k = (blk >> 7) & 3;
  const int b = blk >> 9;
  const float An = -__expf(Alogs[(k * Dd + d) * Nn + n]);
  const float AnE = An * 1.44269504f;
  const size_t bkL = (size_t)(b * Kk + k) * Ll;
  const float2* dP = dd2 + ((size_t)((b * Kk + k) * Dd) + d) * Ll;
  const float2* bP = BC + bkL * Nn + n;
  const int lbeg = s * LCc;
  // phase A: local scan end-state + sum(delta)
  float hA = 0.f, sumD = 0.f;
  {
    const float4* q4 = (const float4*)(dP + lbeg);
    const float2* bl = bP + (size_t)lbeg * Nn;
    for (int it = 0; it < LCc / 4; ++it) {
      const float4 qa = q4[0], qb = q4[1]; q4 += 2;
      const float2 b0 = bl[0], b1 = bl[Nn], b2 = bl[2 * Nn], b3 = bl[3 * Nn];
      bl += 4 * Nn;
      hA = EXP2F(qa.x * AnE) * hA + qa.y * b0.x;
      hA = EXP2F(qa.z * AnE) * hA + qa.w * b1.x;
      hA = EXP2F(qb.x * AnE) * hA + qb.y * b2.x;
      hA = EXP2F(qb.z * AnE) * hA + qb.w * b3.x;
      sumD += (qa.x + qa.z) + (qb.x + qb.z);
    }
  }
  hendS[s][n] = hA;
  if (n == 0) sumDS[s] = sumD;
  __syncthreads();
  // serial carry combine over 16 chunks (half-wave)
  if (tid < 32) {
    float carry = 0.f;
    #pragma unroll
    for (int s2 = 0; s2 < 16; ++s2) {
      carryS[s2][tid] = carry;
      carry = EXP2F(AnE * sumDS[s2]) * carry + hendS[s2][tid];
    }
  }
  __syncthreads();
  // phase B: rerun with carry, emit y (scan part only; Ds*u folded into K5)
  float h = carryS[s][n];
  float* yP = ys + (bkL + lbeg) * Dd + d;
  const float4* q4 = (const float4*)(dP + lbeg);
  const float2* bl = bP + (size_t)lbeg * Nn;
  const bool lead = (n == 0);
  for (int it = 0; it < LCc / 4; ++it) {
    const float4 qa = q4[0], qb = q4[1]; q4 += 2;
    const float2 b0 = bl[0], b1 = bl[Nn], b2 = bl[2 * Nn], b3 = bl[3 * Nn];
    bl += 4 * Nn;
    h = EXP2F(qa.x * AnE) * h + qa.y * b0.x; float p0 = h * b0.y;
    h = EXP2F(qa.z * AnE) * h + qa.w * b1.x; float p1 = h * b1.y;
    h = EXP2F(qb.x * AnE) * h + qb.y * b2.x; float p2 = h * b2.y;
    h = EXP2F(qb.z * AnE) * h + qb.w * b3.x; float p3 = h * b3.y;
    p0 += __shfl_xor(p0, 16); p1 += __shfl_xor(p1, 16);
    p2 += __shfl_xor(p2, 16); p3 += __shfl_xor(p3, 16);
    p0 += __shfl_xor(p0, 8);  p1 += __shfl_xor(p1, 8);
    p2 += __shfl_xor(p2, 8);  p3 += __shfl_xor(p3, 8);
    p0 += __shfl_xor(p0, 4);  p1 += __shfl_xor(p1, 4);
    p2 += __shfl_xor(p2, 4);  p3 += __shfl_xor(p3, 4);
    p0 += __shfl_xor(p0, 2);  p1 += __shfl_xor(p1, 2);
    p2 += __shfl_xor(p2, 2);  p3 += __shfl_xor(p3, 2);
    p0 += __shfl_xor(p0, 1);  p1 += __shfl_xor(p1, 1);
    p2 += __shfl_xor(p2, 1);  p3 += __shfl_xor(p3, 1);
    if (lead) {
      yP[0]      = p0;
      yP[Dd]     = p1;
      yP[2 * Dd] = p2;
      yP[3 * Dd] = p3;
    }
    yP += 4 * Dd;
  }
}

// ---------------- K5: merge + Ds-term + out-LN + SiLU(z)* + out_proj + residual ----------------
__global__ __launch_bounds__(256) void k5_merge(
    const float* __restrict__ ys, const float* __restrict__ zb,
    const float* __restrict__ og, const float* __restrict__ ob,
    const float* __restrict__ Wo, const float* __restrict__ resid,
    const float* __restrict__ xc, const float* __restrict__ DsP,
    float* __restrict__ out)
{
  __shared__ float tS[16][128];
  __shared__ float oS[64][17];
  __shared__ float xcS[16][128];
  const int tid = threadIdx.x;
  const int wv = tid >> 6, lane = tid & 63;
  const int pbase = blockIdx.x * 16;
  const int b = pbase / Ll;
  const int lbase = pbase % Ll;
  {  // stage xc tile (coalesced) for the Ds-term
    const int d = tid >> 1, li0 = (tid & 1) * 8;
    const float4 a4 = *(const float4*)&xc[(b * Dd + d) * Ll + lbase + li0];
    const float4 c4 = *(const float4*)&xc[(b * Dd + d) * Ll + lbase + li0 + 4];
    xcS[li0 + 0][d] = a4.x; xcS[li0 + 1][d] = a4.y;
    xcS[li0 + 2][d] = a4.z; xcS[li0 + 3][d] = a4.w;
    xcS[li0 + 4][d] = c4.x; xcS[li0 + 5][d] = c4.y;
    xcS[li0 + 6][d] = c4.z; xcS[li0 + 7][d] = c4.w;
  }
  float sDs[2];
  #pragma unroll
  for (int m = 0; m < 2; ++m) {
    const int dch = lane + 64 * m;
    sDs[m] = DsP[dch] + DsP[Dd + dch] + DsP[2 * Dd + dch] + DsP[3 * Dd + dch];
  }
  __syncthreads();
  for (int pi = 0; pi < 4; ++pi) {
    const int p = wv * 4 + pi;
    const int l0 = lbase + p;
    const int h = l0 / Ww, w = l0 % Ww;
    const int l1 = w * Hh + h;
    const size_t base = (size_t)(b * Kk) * Ll * Dd;
    float tv[2];
    #pragma unroll
    for (int m = 0; m < 2; ++m) {
      const int dch = lane + 64 * m;
      tv[m] = ys[base + (size_t)l0 * Dd + dch]
            + ys[base + ((size_t)Ll + l1) * Dd + dch]
            + ys[base + ((size_t)2 * Ll + (Ll - 1 - l0)) * Dd + dch]
            + ys[base + ((size_t)3 * Ll + (Ll - 1 - l1)) * Dd + dch]
            + sDs[m] * xcS[p][dch];
    }
    const float mu = wsum64(tv[0] + tv[1]) * (1.0f / 128.0f);
    const float q = wsum64((tv[0] - mu) * (tv[0] - mu) +
                           (tv[1] - mu) * (tv[1] - mu)) * (1.0f / 128.0f);
    const float rs = rsqrtf(q + EPSf);
    #pragma unroll
    for (int m = 0; m < 2; ++m) {
      const int dch = lane + 64 * m;
      const float zz = zb[(size_t)(b * Ll + l0) * Dd + dch];
      const float sig = 1.0f / (1.0f + __expf(-zz));
      tS[p][dch] = ((tv[m] - mu) * rs * og[dch] + ob[dch]) * (zz * sig);
    }
  }
  __syncthreads();
  float acc[4] = {0.f, 0.f, 0.f, 0.f};
  const float4* W4 = (const float4*)Wo;     // out_proj_w (64,128)
  for (int d4 = 0; d4 < 32; ++d4) {
    const float4 w4 = W4[lane * 32 + d4];
    #pragma unroll
    for (int pi = 0; pi < 4; ++pi) {
      const float4 t4 = ((const float4*)tS[wv * 4 + pi])[d4];
      acc[pi] += t4.x * w4.x + t4.y * w4.y + t4.z * w4.z + t4.w * w4.w;
    }
  }
  #pragma unroll
  for (int pi = 0; pi < 4; ++pi) oS[lane][wv * 4 + pi] = acc[pi];
  __syncthreads();
  const int c = tid >> 2, off = (tid & 3) * 4;
  const size_t obase = (size_t)(b * Cc + c) * Ll + lbase + off;
  const float4 r4 = *(const float4*)(resid + obase);
  float4 o4;
  o4.x = oS[c][off + 0] + r4.x;
  o4.y = oS[c][off + 1] + r4.y;
  o4.z = oS[c][off + 2] + r4.z;
  o4.w = oS[c][off + 3] + r4.w;
  *(float4*)(out + obase) = o4;
}

extern "C" void kernel_launch(void* const* d_in, const int* in_sizes, int n_in,
                              void* d_out, int out_size, void* d_ws, size_t ws_size,
                              hipStream_t stream)
{
  (void)in_sizes; (void)n_in; (void)out_size; (void)ws_size;
  const float* fufea1     = (const float*)d_in[0];
  const float* ln_g       = (const float*)d_in[1];
  const float* ln_b       = (const float*)d_in[2];
  const float* in_proj_w  = (const float*)d_in[3];
  const float* conv_w     = (const float*)d_in[4];
  const float* conv_b     = (const float*)d_in[5];
  const float* x_proj_w   = (const float*)d_in[6];
  const float* dt_w       = (const float*)d_in[7];
  const float* dt_b       = (const float*)d_in[8];
  const float* A_logs     = (const float*)d_in[9];
  const float* Ds         = (const float*)d_in[10];
  const float* out_ln_g   = (const float*)d_in[11];
  const float* out_ln_b   = (const float*)d_in[12];
  const float* out_proj_w = (const float*)d_in[13];

  float* ws  = (float*)d_ws;
  float* zb  = ws;                  // (B,L,D)    589824
  float* xc  = ws + 589824;         // (B,D,L)    589824
  float* ysb = ws + 1179648;        // (B,K,L,D)  2359296
  float* xin = ws + 1179648;        // (B,D,L) — overlaps ysb (dead before k4)
  float2* BC  = (float2*)(ws + 3538944);  // (B,K,L,N) float2  -> 1179648 floats
  float2* dd2 = (float2*)(ws + 4718592);  // (B,K,D,L) float2  -> 4718592 floats
  // total: 9437184 floats = 37.75 MB

  k1_ln_inproj<<<288, 256, 0, stream>>>(fufea1, ln_g, ln_b, in_proj_w, xin, zb);
  k2_conv<<<2304, 256, 0, stream>>>(xin, conv_w, conv_b, xc);
  k3_proj<<<576, 512, 0, stream>>>(xc, x_proj_w, dt_w, dt_b, dd2, BC);
  k4_scan<<<1024, 512, 0, stream>>>(dd2, BC, A_logs, ysb);
  k5_merge<<<288, 256, 0, stream>>>(ysb, zb, out_ln_g, out_ln_b, out_proj_w, fufea1,
                                    xc, Ds, (float*)d_out);
}

// Round 3
// 220.984 us; speedup vs baseline: 1.6007x; 1.2215x over previous
//
#include <hip/hip_runtime.h>

#define Cc 64
#define Dd 128
#define Nn 32
#define Kk 4
#define Rr 4
#define Bb 2
#define Hh 48
#define Ww 48
#define Ll 2304
#define EPSf 1e-5f
#define LCc 144   // scan chunk length = L/16

#if __has_builtin(__builtin_amdgcn_exp2f)
#define EXP2F __builtin_amdgcn_exp2f
#else
#define EXP2F exp2f
#endif

__device__ __forceinline__ float wsum64(float v) {
  v += __shfl_xor(v, 32);
  v += __shfl_xor(v, 16);
  v += __shfl_xor(v, 8);
  v += __shfl_xor(v, 4);
  v += __shfl_xor(v, 2);
  v += __shfl_xor(v, 1);
  return v;
}

// ---------------- K1: pre-LN (over C) + in_proj (C -> 2D), split x/z ----------------
__global__ __launch_bounds__(256) void k1_ln_inproj(
    const float* __restrict__ x, const float* __restrict__ g,
    const float* __restrict__ bta, const float* __restrict__ Wp,
    float* __restrict__ xin, float* __restrict__ zb)
{
  __shared__ float xS[16][65];
  __shared__ float xnS[16][64];
  __shared__ float xaS[128][17];
  const int tid = threadIdx.x;
  const int wv = tid >> 6, lane = tid & 63;
  const int pbase = blockIdx.x * 16;       // 4608 pixels total, no b-straddle
  const int b = pbase / Ll;
  const int lbase = pbase % Ll;
  {  // coalesced staging: thread -> (c, 4 consecutive l)
    const int c = tid >> 2, li0 = (tid & 3) * 4;
    const float4 v4 = *(const float4*)&x[(b * Cc + c) * Ll + lbase + li0];
    xS[li0 + 0][c] = v4.x;
    xS[li0 + 1][c] = v4.y;
    xS[li0 + 2][c] = v4.z;
    xS[li0 + 3][c] = v4.w;
  }
  __syncthreads();
  const float gv = g[lane], bv = bta[lane];
  for (int pi = 0; pi < 4; ++pi) {
    const int p = wv * 4 + pi;
    const float v = xS[p][lane];
    const float mu = wsum64(v) * (1.0f / 64.0f);
    const float dv = v - mu;
    const float var = wsum64(dv * dv) * (1.0f / 64.0f);
    const float rs = rsqrtf(var + EPSf);
    xnS[p][lane] = dv * rs * gv + bv;
  }
  __syncthreads();
  float acc[4][4];
  #pragma unroll
  for (int pi = 0; pi < 4; ++pi)
    #pragma unroll
    for (int m = 0; m < 4; ++m) acc[pi][m] = 0.f;
  const float4* W4 = (const float4*)Wp;
  #pragma unroll 4
  for (int c4 = 0; c4 < 16; ++c4) {
    float4 xn4[4];
    #pragma unroll
    for (int pi = 0; pi < 4; ++pi)
      xn4[pi] = ((const float4*)xnS[wv * 4 + pi])[c4];
    #pragma unroll
    for (int m = 0; m < 4; ++m) {
      const float4 w4 = W4[(lane + 64 * m) * 16 + c4];
      #pragma unroll
      for (int pi = 0; pi < 4; ++pi)
        acc[pi][m] += xn4[pi].x * w4.x + xn4[pi].y * w4.y +
                      xn4[pi].z * w4.z + xn4[pi].w * w4.w;
    }
  }
  #pragma unroll
  for (int pi = 0; pi < 4; ++pi) {
    const int l = lbase + wv * 4 + pi;
    zb[(b * Ll + l) * Dd + lane]      = acc[pi][2];
    zb[(b * Ll + l) * Dd + lane + 64] = acc[pi][3];
    xaS[lane][wv * 4 + pi]      = acc[pi][0];
    xaS[lane + 64][wv * 4 + pi] = acc[pi][1];
  }
  __syncthreads();
  const int d = tid >> 1, off = (tid & 1) * 8;
  float* dst = &xin[(b * Dd + d) * Ll + lbase + off];
  #pragma unroll
  for (int i = 0; i < 8; ++i) dst[i] = xaS[d][off + i];
}

// ---------------- K2: depthwise 3x3 conv (SAME) + bias + SiLU ----------------
__global__ __launch_bounds__(256) void k2_conv(
    const float* __restrict__ xin, const float* __restrict__ cw,
    const float* __restrict__ cb, float* __restrict__ xc)
{
  const int idx = blockIdx.x * 256 + threadIdx.x;   // exactly B*D*L threads
  const int l = idx % Ll;
  const int bd = idx / Ll;
  const int d = bd % Dd;
  const int h = l / Ww, w = l % Ww;
  float acc = cb[d];
  #pragma unroll
  for (int i = 0; i < 3; ++i) {
    const int hh = h + i - 1;
    if (hh < 0 || hh >= Hh) continue;
    #pragma unroll
    for (int j = 0; j < 3; ++j) {
      const int ww2 = w + j - 1;
      if (ww2 < 0 || ww2 >= Ww) continue;
      acc += xin[bd * Ll + hh * Ww + ww2] * cw[d * 9 + i * 3 + j];
    }
  }
  const float sig = 1.0f / (1.0f + __expf(-acc));
  xc[idx] = acc * sig;
}

// ---------------- K3: projections; emits {delta, delta*u} + separate B, C ----------------
__global__ __launch_bounds__(512) void k3_proj(
    const float* __restrict__ xc, const float* __restrict__ xpw,
    const float* __restrict__ dtw, const float* __restrict__ dtb,
    float2* __restrict__ dd2, float* __restrict__ Bm, float* __restrict__ Cm)
{
  __shared__ float xvS[8][132];
  __shared__ float dtsS[8][16];
  const int t = threadIdx.x;
  const int pb = blockIdx.x * 8;
  const int b = pb / Ll;
  const int lb = pb % Ll;
  {  // stage 8 pixels x 128 d
    const int d = t >> 2;
    const int li0 = (t & 3) * 2;
    const float2 v2 = *(const float2*)&xc[(b * Dd + d) * Ll + lb + li0];
    xvS[li0][d]     = v2.x;
    xvS[li0 + 1][d] = v2.y;
  }
  __syncthreads();
  if (t < 272) {
    const int k = t / 68, c = t % 68;
    const size_t bkL = (size_t)(b * Kk + k) * Ll;
    float acc[8];
    #pragma unroll
    for (int pi = 0; pi < 8; ++pi) acc[pi] = 0.f;
    const float4* w4p = (const float4*)(xpw + (k * 68 + c) * 128);
    for (int d4 = 0; d4 < 32; ++d4) {
      const float4 w4 = w4p[d4];
      #pragma unroll
      for (int pi = 0; pi < 8; ++pi) {
        const float4 x4 = ((const float4*)xvS[pi])[d4];
        acc[pi] += x4.x * w4.x + x4.y * w4.y + x4.z * w4.z + x4.w * w4.w;
      }
    }
    #pragma unroll
    for (int pi = 0; pi < 8; ++pi) {
      const int l0 = lb + pi;
      const int h = l0 / Ww, w = l0 % Ww;
      int lk;
      if      (k == 0) lk = l0;
      else if (k == 1) lk = w * Hh + h;
      else if (k == 2) lk = Ll - 1 - l0;
      else             lk = Ll - 1 - (w * Hh + h);
      if (c < Rr)            dtsS[pi][k * 4 + c] = acc[pi];
      else if (c < Rr + Nn)  Bm[(bkL + lk) * Nn + (c - Rr)] = acc[pi];
      else                   Cm[(bkL + lk) * Nn + (c - Rr - Nn)] = acc[pi];
    }
  }
  __syncthreads();
  {  // delta + softplus + pack {delta, delta*u}
    const int k = t >> 7, dd = t & 127;
    const float4 dw = *(const float4*)&dtw[(k * Dd + dd) * 4];
    const float biasv = dtb[k * Dd + dd];
    float2* drow = dd2 + ((size_t)((b * Kk + k) * Dd) + dd) * Ll;
    float2 buf[8];
    #pragma unroll
    for (int pi = 0; pi < 8; ++pi) {
      const float a = biasv
          + dtsS[pi][k * 4 + 0] * dw.x + dtsS[pi][k * 4 + 1] * dw.y
          + dtsS[pi][k * 4 + 2] * dw.z + dtsS[pi][k * 4 + 3] * dw.w;
      const float sp = (a > 20.f) ? a : log1pf(__expf(a));
      buf[pi] = make_float2(sp, sp * xvS[pi][dd]);
    }
    if (k == 0) {
      float4* f4 = (float4*)(drow + lb);
      #pragma unroll
      for (int j = 0; j < 4; ++j)
        f4[j] = make_float4(buf[2 * j].x, buf[2 * j].y, buf[2 * j + 1].x, buf[2 * j + 1].y);
    } else if (k == 2) {
      float4* f4 = (float4*)(drow + (Ll - 8 - lb));
      #pragma unroll
      for (int j = 0; j < 4; ++j)
        f4[j] = make_float4(buf[7 - 2 * j].x, buf[7 - 2 * j].y, buf[6 - 2 * j].x, buf[6 - 2 * j].y);
    } else {
      #pragma unroll
      for (int pi = 0; pi < 8; ++pi) {
        const int l0 = lb + pi;
        const int h = l0 / Ww, w = l0 % Ww;
        int lk = w * Hh + h;
        if (k == 3) lk = Ll - 1 - lk;
        drow[lk] = buf[pi];
      }
    }
  }
}

// ---------------- K4: chunked two-pass selective scan, S=16, LDS-deferred y-reduce ----------------
// block = (b,k,d): 1024 blocks x 512 threads (16 chunks x 32 state-lanes).
// ys layout: (b,k,d,l) -- each block writes one contiguous L-row.
__global__ __launch_bounds__(512) void k4_scan(
    const float2* __restrict__ dd2, const float* __restrict__ Bm,
    const float* __restrict__ Cm, const float* __restrict__ Alogs,
    float* __restrict__ ys)
{
  __shared__ float hendS[16][32];
  __shared__ float carryS[16][32];
  __shared__ float sumDS[16];
  __shared__ float pS[16][8][36];
  const int tid = threadIdx.x;
  const int s = tid >> 5, n = tid & 31;
  const int blk = blockIdx.x;
  const int d = blk & 127;
  const int k = (blk >> 7) & 3;
  const int b = blk >> 9;
  const float An = -__expf(Alogs[(k * Dd + d) * Nn + n]);
  const float AnE = An * 1.44269504f;
  const size_t bkL = (size_t)(b * Kk + k) * Ll;
  const float2* dP = dd2 + ((size_t)((b * Kk + k) * Dd) + d) * Ll;
  const float* bP = Bm + bkL * Nn + n;
  const float* cP = Cm + bkL * Nn + n;
  const int lbeg = s * LCc;
  // phase A: local scan end-state + sum(delta)
  float hA = 0.f, sumD = 0.f;
  {
    const float4* q4 = (const float4*)(dP + lbeg);
    const float* bl = bP + (size_t)lbeg * Nn;
    for (int it = 0; it < LCc / 4; ++it) {
      const float4 qa = q4[0], qb = q4[1]; q4 += 2;
      const float b0 = bl[0], b1 = bl[Nn], b2 = bl[2 * Nn], b3 = bl[3 * Nn];
      bl += 4 * Nn;
      hA = EXP2F(qa.x * AnE) * hA + qa.y * b0;
      hA = EXP2F(qa.z * AnE) * hA + qa.w * b1;
      hA = EXP2F(qb.x * AnE) * hA + qb.y * b2;
      hA = EXP2F(qb.z * AnE) * hA + qb.w * b3;
      sumD += (qa.x + qa.z) + (qb.x + qb.z);
    }
  }
  hendS[s][n] = hA;
  if (n == 0) sumDS[s] = sumD;
  __syncthreads();
  // serial carry combine over 16 chunks (half-wave)
  if (tid < 32) {
    float carry = 0.f;
    #pragma unroll
    for (int s2 = 0; s2 < 16; ++s2) {
      carryS[s2][tid] = carry;
      carry = EXP2F(AnE * sumDS[s2]) * carry + hendS[s2][tid];
    }
  }
  __syncthreads();
  // phase B: rerun with carry; per-lane p into LDS tile, reduce every 8 steps
  float h = carryS[s][n];
  float* yP = ys + ((size_t)((b * Kk + k) * Dd) + d) * Ll + lbeg;
  const float4* q4 = (const float4*)(dP + lbeg);
  const float* bl = bP + (size_t)lbeg * Nn;
  const float* cl = cP + (size_t)lbeg * Nn;
  const int rrow = n & 7, qtr = n >> 3;
  for (int t8 = 0; t8 < LCc / 8; ++t8) {
    #pragma unroll
    for (int half = 0; half < 2; ++half) {
      const float4 qa = q4[0], qb = q4[1]; q4 += 2;
      const float b0 = bl[0], b1 = bl[Nn], b2 = bl[2 * Nn], b3 = bl[3 * Nn];
      const float c0 = cl[0], c1 = cl[Nn], c2 = cl[2 * Nn], c3 = cl[3 * Nn];
      bl += 4 * Nn; cl += 4 * Nn;
      h = EXP2F(qa.x * AnE) * h + qa.y * b0; pS[s][half * 4 + 0][n] = h * c0;
      h = EXP2F(qa.z * AnE) * h + qa.w * b1; pS[s][half * 4 + 1][n] = h * c1;
      h = EXP2F(qb.x * AnE) * h + qb.y * b2; pS[s][half * 4 + 2][n] = h * c2;
      h = EXP2F(qb.z * AnE) * h + qb.w * b3; pS[s][half * 4 + 3][n] = h * c3;
    }
    // reduce the 8-step tile: lane sums a quarter-row, 2 shuffles combine
    const float4 a4 = *(const float4*)&pS[s][rrow][qtr * 8];
    const float4 d4 = *(const float4*)&pS[s][rrow][qtr * 8 + 4];
    float sum = ((a4.x + a4.y) + (a4.z + a4.w)) + ((d4.x + d4.y) + (d4.z + d4.w));
    sum += __shfl_xor(sum, 8);
    sum += __shfl_xor(sum, 16);
    if (n < 8) yP[t8 * 8 + n] = sum;
  }
}

// ---------------- K5: merge + Ds-term + out-LN + SiLU(z)* + out_proj + residual ----------------
__global__ __launch_bounds__(256) void k5_merge(
    const float* __restrict__ ys, const float* __restrict__ zb,
    const float* __restrict__ og, const float* __restrict__ ob,
    const float* __restrict__ Wo, const float* __restrict__ resid,
    const float* __restrict__ xc, const float* __restrict__ DsP,
    float* __restrict__ out)
{
  __shared__ float ysS[4][16][128];
  __shared__ float tS[16][128];
  __shared__ float oS[64][17];
  __shared__ float xcS[16][128];
  const int tid = threadIdx.x;
  const int wv = tid >> 6, lane = tid & 63;
  const int pbase = blockIdx.x * 16;
  const int b = pbase / Ll;
  const int lbase = pbase % Ll;
  const int hrow = lbase / Ww, w0 = lbase % Ww;   // 16 | 48 => whole tile in one image row
  {  // stage xc tile + 4-direction ys tiles (ys layout: (b,k,d,l))
    const int dch = tid & 127, seg = tid >> 7;    // seg in {0,1}, 8 l each
    {
      const float4 a4 = *(const float4*)&xc[(b * Dd + dch) * Ll + lbase + seg * 8];
      const float4 c4 = *(const float4*)&xc[(b * Dd + dch) * Ll + lbase + seg * 8 + 4];
      xcS[seg * 8 + 0][dch] = a4.x; xcS[seg * 8 + 1][dch] = a4.y;
      xcS[seg * 8 + 2][dch] = a4.z; xcS[seg * 8 + 3][dch] = a4.w;
      xcS[seg * 8 + 4][dch] = c4.x; xcS[seg * 8 + 5][dch] = c4.y;
      xcS[seg * 8 + 6][dch] = c4.z; xcS[seg * 8 + 7][dch] = c4.w;
    }
    {  // dir 0: contiguous ascending
      const size_t r0 = ((size_t)(b * Kk + 0) * Dd + dch) * Ll + lbase + seg * 8;
      const float4 a4 = *(const float4*)&ys[r0];
      const float4 c4 = *(const float4*)&ys[r0 + 4];
      ysS[0][seg * 8 + 0][dch] = a4.x; ysS[0][seg * 8 + 1][dch] = a4.y;
      ysS[0][seg * 8 + 2][dch] = a4.z; ysS[0][seg * 8 + 3][dch] = a4.w;
      ysS[0][seg * 8 + 4][dch] = c4.x; ysS[0][seg * 8 + 5][dch] = c4.y;
      ysS[0][seg * 8 + 6][dch] = c4.z; ysS[0][seg * 8 + 7][dch] = c4.w;
    }
    {  // dir 2: contiguous, reversed (scan pos L-1-l0)
      const size_t r2 = ((size_t)(b * Kk + 2) * Dd + dch) * Ll + (Ll - 16 - lbase) + seg * 8;
      const float4 a4 = *(const float4*)&ys[r2];
      const float4 c4 = *(const float4*)&ys[r2 + 4];
      ysS[2][15 - seg * 8 - 0][dch] = a4.x; ysS[2][15 - seg * 8 - 1][dch] = a4.y;
      ysS[2][15 - seg * 8 - 2][dch] = a4.z; ysS[2][15 - seg * 8 - 3][dch] = a4.w;
      ysS[2][15 - seg * 8 - 4][dch] = c4.x; ysS[2][15 - seg * 8 - 5][dch] = c4.y;
      ysS[2][15 - seg * 8 - 6][dch] = c4.z; ysS[2][15 - seg * 8 - 7][dch] = c4.w;
    }
    {  // dirs 1,3: scan pos l1 = w*Hh + h (scattered, L2-resident)
      const size_t r1 = ((size_t)(b * Kk + 1) * Dd + dch) * Ll;
      const size_t r3 = ((size_t)(b * Kk + 3) * Dd + dch) * Ll;
      #pragma unroll
      for (int j = 0; j < 8; ++j) {
        const int p = seg * 8 + j;
        const int l1 = (w0 + p) * Hh + hrow;
        ysS[1][p][dch] = ys[r1 + l1];
        ysS[3][p][dch] = ys[r3 + (Ll - 1 - l1)];
      }
    }
  }
  float sDs[2];
  #pragma unroll
  for (int m = 0; m < 2; ++m) {
    const int dch = lane + 64 * m;
    sDs[m] = DsP[dch] + DsP[Dd + dch] + DsP[2 * Dd + dch] + DsP[3 * Dd + dch];
  }
  __syncthreads();
  for (int pi = 0; pi < 4; ++pi) {
    const int p = wv * 4 + pi;
    const int l0 = lbase + p;
    float tv[2];
    #pragma unroll
    for (int m = 0; m < 2; ++m) {
      const int dch = lane + 64 * m;
      tv[m] = ysS[0][p][dch] + ysS[1][p][dch] + ysS[2][p][dch] + ysS[3][p][dch]
            + sDs[m] * xcS[p][dch];
    }
    const float mu = wsum64(tv[0] + tv[1]) * (1.0f / 128.0f);
    const float q = wsum64((tv[0] - mu) * (tv[0] - mu) +
                           (tv[1] - mu) * (tv[1] - mu)) * (1.0f / 128.0f);
    const float rs = rsqrtf(q + EPSf);
    #pragma unroll
    for (int m = 0; m < 2; ++m) {
      const int dch = lane + 64 * m;
      const float zz = zb[(size_t)(b * Ll + l0) * Dd + dch];
      const float sig = 1.0f / (1.0f + __expf(-zz));
      tS[p][dch] = ((tv[m] - mu) * rs * og[dch] + ob[dch]) * (zz * sig);
    }
  }
  __syncthreads();
  float acc[4] = {0.f, 0.f, 0.f, 0.f};
  const float4* W4 = (const float4*)Wo;     // out_proj_w (64,128)
  for (int d4 = 0; d4 < 32; ++d4) {
    const float4 w4 = W4[lane * 32 + d4];
    #pragma unroll
    for (int pi = 0; pi < 4; ++pi) {
      const float4 t4 = ((const float4*)tS[wv * 4 + pi])[d4];
      acc[pi] += t4.x * w4.x + t4.y * w4.y + t4.z * w4.z + t4.w * w4.w;
    }
  }
  #pragma unroll
  for (int pi = 0; pi < 4; ++pi) oS[lane][wv * 4 + pi] = acc[pi];
  __syncthreads();
  const int c = tid >> 2, off = (tid & 3) * 4;
  const size_t obase = (size_t)(b * Cc + c) * Ll + lbase + off;
  const float4 r4 = *(const float4*)(resid + obase);
  float4 o4;
  o4.x = oS[c][off + 0] + r4.x;
  o4.y = oS[c][off + 1] + r4.y;
  o4.z = oS[c][off + 2] + r4.z;
  o4.w = oS[c][off + 3] + r4.w;
  *(float4*)(out + obase) = o4;
}

extern "C" void kernel_launch(void* const* d_in, const int* in_sizes, int n_in,
                              void* d_out, int out_size, void* d_ws, size_t ws_size,
                              hipStream_t stream)
{
  (void)in_sizes; (void)n_in; (void)out_size; (void)ws_size;
  const float* fufea1     = (const float*)d_in[0];
  const float* ln_g       = (const float*)d_in[1];
  const float* ln_b       = (const float*)d_in[2];
  const float* in_proj_w  = (const float*)d_in[3];
  const float* conv_w     = (const float*)d_in[4];
  const float* conv_b     = (const float*)d_in[5];
  const float* x_proj_w   = (const float*)d_in[6];
  const float* dt_w       = (const float*)d_in[7];
  const float* dt_b       = (const float*)d_in[8];
  const float* A_logs     = (const float*)d_in[9];
  const float* Ds         = (const float*)d_in[10];
  const float* out_ln_g   = (const float*)d_in[11];
  const float* out_ln_b   = (const float*)d_in[12];
  const float* out_proj_w = (const float*)d_in[13];

  float* ws  = (float*)d_ws;
  float* zb  = ws;                  // (B,L,D)    589824
  float* xc  = ws + 589824;         // (B,D,L)    589824
  float* ysb = ws + 1179648;        // (B,K,D,L)  2359296
  float* xin = ws + 1179648;        // (B,D,L) — overlaps ysb (dead before k4)
  float* Bm  = ws + 3538944;        // (B,K,L,N)  589824
  float* Cm  = ws + 4128768;        // (B,K,L,N)  589824
  float2* dd2 = (float2*)(ws + 4718592);  // (B,K,D,L) float2 -> 4718592 floats
  // total: 9437184 floats = 37.75 MB

  k1_ln_inproj<<<288, 256, 0, stream>>>(fufea1, ln_g, ln_b, in_proj_w, xin, zb);
  k2_conv<<<2304, 256, 0, stream>>>(xin, conv_w, conv_b, xc);
  k3_proj<<<576, 512, 0, stream>>>(xc, x_proj_w, dt_w, dt_b, dd2, Bm, Cm);
  k4_scan<<<1024, 512, 0, stream>>>(dd2, Bm, Cm, A_logs, ysb);
  k5_merge<<<288, 256, 0, stream>>>(ysb, zb, out_ln_g, out_ln_b, out_proj_w, fufea1,
                                    xc, Ds, (float*)d_out);
}

// Round 4
// 220.318 us; speedup vs baseline: 1.6056x; 1.0030x over previous
//
#include <hip/hip_runtime.h>

#define Cc 64
#define Dd 128
#define Nn 32
#define Kk 4
#define Rr 4
#define Bb 2
#define Hh 48
#define Ww 48
#define Ll 2304
#define EPSf 1e-5f
#define LCc 144   // scan chunk length = L/16

#if __has_builtin(__builtin_amdgcn_exp2f)
#define EXP2F __builtin_amdgcn_exp2f
#else
#define EXP2F exp2f
#endif

__device__ __forceinline__ float wsum64(float v) {
  v += __shfl_xor(v, 32);
  v += __shfl_xor(v, 16);
  v += __shfl_xor(v, 8);
  v += __shfl_xor(v, 4);
  v += __shfl_xor(v, 2);
  v += __shfl_xor(v, 1);
  return v;
}

// ---------------- K1: pre-LN (over C) + in_proj (C -> 2D), split x/z ----------------
__global__ __launch_bounds__(256) void k1_ln_inproj(
    const float* __restrict__ x, const float* __restrict__ g,
    const float* __restrict__ bta, const float* __restrict__ Wp,
    float* __restrict__ xin, float* __restrict__ zb)
{
  __shared__ float xS[16][65];
  __shared__ float xnS[16][64];
  __shared__ float xaS[128][17];
  const int tid = threadIdx.x;
  const int wv = tid >> 6, lane = tid & 63;
  const int pbase = blockIdx.x * 16;       // 4608 pixels total, no b-straddle
  const int b = pbase / Ll;
  const int lbase = pbase % Ll;
  {  // coalesced staging: thread -> (c, 4 consecutive l)
    const int c = tid >> 2, li0 = (tid & 3) * 4;
    const float4 v4 = *(const float4*)&x[(b * Cc + c) * Ll + lbase + li0];
    xS[li0 + 0][c] = v4.x;
    xS[li0 + 1][c] = v4.y;
    xS[li0 + 2][c] = v4.z;
    xS[li0 + 3][c] = v4.w;
  }
  __syncthreads();
  const float gv = g[lane], bv = bta[lane];
  for (int pi = 0; pi < 4; ++pi) {
    const int p = wv * 4 + pi;
    const float v = xS[p][lane];
    const float mu = wsum64(v) * (1.0f / 64.0f);
    const float dv = v - mu;
    const float var = wsum64(dv * dv) * (1.0f / 64.0f);
    const float rs = rsqrtf(var + EPSf);
    xnS[p][lane] = dv * rs * gv + bv;
  }
  __syncthreads();
  float acc[4][4];
  #pragma unroll
  for (int pi = 0; pi < 4; ++pi)
    #pragma unroll
    for (int m = 0; m < 4; ++m) acc[pi][m] = 0.f;
  const float4* W4 = (const float4*)Wp;
  #pragma unroll 4
  for (int c4 = 0; c4 < 16; ++c4) {
    float4 xn4[4];
    #pragma unroll
    for (int pi = 0; pi < 4; ++pi)
      xn4[pi] = ((const float4*)xnS[wv * 4 + pi])[c4];
    #pragma unroll
    for (int m = 0; m < 4; ++m) {
      const float4 w4 = W4[(lane + 64 * m) * 16 + c4];
      #pragma unroll
      for (int pi = 0; pi < 4; ++pi)
        acc[pi][m] += xn4[pi].x * w4.x + xn4[pi].y * w4.y +
                      xn4[pi].z * w4.z + xn4[pi].w * w4.w;
    }
  }
  #pragma unroll
  for (int pi = 0; pi < 4; ++pi) {
    const int l = lbase + wv * 4 + pi;
    zb[(b * Ll + l) * Dd + lane]      = acc[pi][2];
    zb[(b * Ll + l) * Dd + lane + 64] = acc[pi][3];
    xaS[lane][wv * 4 + pi]      = acc[pi][0];
    xaS[lane + 64][wv * 4 + pi] = acc[pi][1];
  }
  __syncthreads();
  const int d = tid >> 1, off = (tid & 1) * 8;
  float* dst = &xin[(b * Dd + d) * Ll + lbase + off];
  #pragma unroll
  for (int i = 0; i < 8; ++i) dst[i] = xaS[d][off + i];
}

// ---------------- K3: conv3x3+SiLU (fused) + projections -> xc, {delta,delta*u}, B, C ----------------
// 8 pixels/block (one row segment; 8 | 48 so no row straddle). Conv needs a
// 3-row x 10-col halo tile of xin per d: 15 KB LDS, zero-padded (SAME).
__global__ __launch_bounds__(512) void k3_proj(
    const float* __restrict__ xin, const float* __restrict__ cw,
    const float* __restrict__ cb, const float* __restrict__ xpw,
    const float* __restrict__ dtw, const float* __restrict__ dtb,
    float* __restrict__ xc, float2* __restrict__ dd2,
    float* __restrict__ Bm, float* __restrict__ Cm)
{
  __shared__ float xinS[128][30];
  __shared__ float xvS[8][132];
  __shared__ float dtsS[8][16];
  const int t = threadIdx.x;
  const int pb = blockIdx.x * 8;
  const int b = pb / Ll;
  const int lb = pb % Ll;
  const int h0 = lb / Ww, w0 = lb % Ww;
  // stage 3 rows x 10 cols x 128 d of xin, zero-padded at image borders
  for (int i = t; i < 3840; i += 512) {
    const int d = i / 30, j = i % 30;
    const int r = j / 10, c = j % 10;
    const int hh = h0 + r - 1, ww = w0 + c - 1;
    float v = 0.f;
    if (hh >= 0 && hh < Hh && ww >= 0 && ww < Ww)
      v = xin[(b * Dd + d) * Ll + hh * Ww + ww];
    xinS[d][j] = v;
  }
  __syncthreads();
  // depthwise conv + bias + SiLU -> xvS (pixel-major for the GEMM below)
  for (int i = t; i < 1024; i += 512) {
    const int pi = i >> 7, d = i & 127;
    float acc = cb[d];
    #pragma unroll
    for (int r = 0; r < 3; ++r)
      #pragma unroll
      for (int c = 0; c < 3; ++c)
        acc += xinS[d][r * 10 + pi + c] * cw[d * 9 + r * 3 + c];
    const float sig = 1.0f / (1.0f + __expf(-acc));
    xvS[pi][d] = acc * sig;
  }
  __syncthreads();
  // coalesced xc write (for k5's Ds-term)
  for (int i = t; i < 1024; i += 512) {
    const int d = i >> 3, pi = i & 7;
    xc[(b * Dd + d) * Ll + lb + pi] = xvS[pi][d];
  }
  if (t < 272) {
    const int k = t / 68, c = t % 68;
    const size_t bkL = (size_t)(b * Kk + k) * Ll;
    float acc[8];
    #pragma unroll
    for (int pi = 0; pi < 8; ++pi) acc[pi] = 0.f;
    const float4* w4p = (const float4*)(xpw + (k * 68 + c) * 128);
    for (int d4 = 0; d4 < 32; ++d4) {
      const float4 w4 = w4p[d4];
      #pragma unroll
      for (int pi = 0; pi < 8; ++pi) {
        const float4 x4 = ((const float4*)xvS[pi])[d4];
        acc[pi] += x4.x * w4.x + x4.y * w4.y + x4.z * w4.z + x4.w * w4.w;
      }
    }
    #pragma unroll
    for (int pi = 0; pi < 8; ++pi) {
      const int l0 = lb + pi;
      const int h = l0 / Ww, w = l0 % Ww;
      int lk;
      if      (k == 0) lk = l0;
      else if (k == 1) lk = w * Hh + h;
      else if (k == 2) lk = Ll - 1 - l0;
      else             lk = Ll - 1 - (w * Hh + h);
      if (c < Rr)            dtsS[pi][k * 4 + c] = acc[pi];
      else if (c < Rr + Nn)  Bm[(bkL + lk) * Nn + (c - Rr)] = acc[pi];
      else                   Cm[(bkL + lk) * Nn + (c - Rr - Nn)] = acc[pi];
    }
  }
  __syncthreads();
  {  // delta + softplus + pack {delta, delta*u}
    const int k = t >> 7, dd = t & 127;
    const float4 dw = *(const float4*)&dtw[(k * Dd + dd) * 4];
    const float biasv = dtb[k * Dd + dd];
    float2* drow = dd2 + ((size_t)((b * Kk + k) * Dd) + dd) * Ll;
    float2 buf[8];
    #pragma unroll
    for (int pi = 0; pi < 8; ++pi) {
      const float a = biasv
          + dtsS[pi][k * 4 + 0] * dw.x + dtsS[pi][k * 4 + 1] * dw.y
          + dtsS[pi][k * 4 + 2] * dw.z + dtsS[pi][k * 4 + 3] * dw.w;
      const float sp = (a > 20.f) ? a : log1pf(__expf(a));
      buf[pi] = make_float2(sp, sp * xvS[pi][dd]);
    }
    if (k == 0) {
      float4* f4 = (float4*)(drow + lb);
      #pragma unroll
      for (int j = 0; j < 4; ++j)
        f4[j] = make_float4(buf[2 * j].x, buf[2 * j].y, buf[2 * j + 1].x, buf[2 * j + 1].y);
    } else if (k == 2) {
      float4* f4 = (float4*)(drow + (Ll - 8 - lb));
      #pragma unroll
      for (int j = 0; j < 4; ++j)
        f4[j] = make_float4(buf[7 - 2 * j].x, buf[7 - 2 * j].y, buf[6 - 2 * j].x, buf[6 - 2 * j].y);
    } else {
      #pragma unroll
      for (int pi = 0; pi < 8; ++pi) {
        const int l0 = lb + pi;
        const int h = l0 / Ww, w = l0 % Ww;
        int lk = w * Hh + h;
        if (k == 3) lk = Ll - 1 - lk;
        drow[lk] = buf[pi];
      }
    }
  }
}

// ---------------- K4: chunked two-pass selective scan, S=16, LDS-deferred y-reduce ----------------
// block = (b,k,d): 1024 blocks x 512 threads (16 chunks x 32 state-lanes).
// ys layout: (b,k,d,l) -- each block writes one contiguous L-row.
__global__ __launch_bounds__(512) void k4_scan(
    const float2* __restrict__ dd2, const float* __restrict__ Bm,
    const float* __restrict__ Cm, const float* __restrict__ Alogs,
    float* __restrict__ ys)
{
  __shared__ float hendS[16][32];
  __shared__ float carryS[16][32];
  __shared__ float sumDS[16];
  __shared__ float pS[16][8][36];
  const int tid = threadIdx.x;
  const int s = tid >> 5, n = tid & 31;
  const int blk = blockIdx.x;
  const int d = blk & 127;
  const int k = (blk >> 7) & 3;
  const int b = blk >> 9;
  const float An = -__expf(Alogs[(k * Dd + d) * Nn + n]);
  const float AnE = An * 1.44269504f;
  const size_t bkL = (size_t)(b * Kk + k) * Ll;
  const float2* dP = dd2 + ((size_t)((b * Kk + k) * Dd) + d) * Ll;
  const float* bP = Bm + bkL * Nn + n;
  const float* cP = Cm + bkL * Nn + n;
  const int lbeg = s * LCc;
  // phase A: local scan end-state + sum(delta)
  float hA = 0.f, sumD = 0.f;
  {
    const float4* q4 = (const float4*)(dP + lbeg);
    const float* bl = bP + (size_t)lbeg * Nn;
    for (int it = 0; it < LCc / 4; ++it) {
      const float4 qa = q4[0], qb = q4[1]; q4 += 2;
      const float b0 = bl[0], b1 = bl[Nn], b2 = bl[2 * Nn], b3 = bl[3 * Nn];
      bl += 4 * Nn;
      hA = EXP2F(qa.x * AnE) * hA + qa.y * b0;
      hA = EXP2F(qa.z * AnE) * hA + qa.w * b1;
      hA = EXP2F(qb.x * AnE) * hA + qb.y * b2;
      hA = EXP2F(qb.z * AnE) * hA + qb.w * b3;
      sumD += (qa.x + qa.z) + (qb.x + qb.z);
    }
  }
  hendS[s][n] = hA;
  if (n == 0) sumDS[s] = sumD;
  __syncthreads();
  // serial carry combine over 16 chunks (half-wave)
  if (tid < 32) {
    float carry = 0.f;
    #pragma unroll
    for (int s2 = 0; s2 < 16; ++s2) {
      carryS[s2][tid] = carry;
      carry = EXP2F(AnE * sumDS[s2]) * carry + hendS[s2][tid];
    }
  }
  __syncthreads();
  // phase B: rerun with carry; per-lane p into LDS tile, reduce every 8 steps
  float h = carryS[s][n];
  float* yP = ys + ((size_t)((b * Kk + k) * Dd) + d) * Ll + lbeg;
  const float4* q4 = (const float4*)(dP + lbeg);
  const float* bl = bP + (size_t)lbeg * Nn;
  const float* cl = cP + (size_t)lbeg * Nn;
  const int rrow = n & 7, qtr = n >> 3;
  for (int t8 = 0; t8 < LCc / 8; ++t8) {
    #pragma unroll
    for (int half = 0; half < 2; ++half) {
      const float4 qa = q4[0], qb = q4[1]; q4 += 2;
      const float b0 = bl[0], b1 = bl[Nn], b2 = bl[2 * Nn], b3 = bl[3 * Nn];
      const float c0 = cl[0], c1 = cl[Nn], c2 = cl[2 * Nn], c3 = cl[3 * Nn];
      bl += 4 * Nn; cl += 4 * Nn;
      h = EXP2F(qa.x * AnE) * h + qa.y * b0; pS[s][half * 4 + 0][n] = h * c0;
      h = EXP2F(qa.z * AnE) * h + qa.w * b1; pS[s][half * 4 + 1][n] = h * c1;
      h = EXP2F(qb.x * AnE) * h + qb.y * b2; pS[s][half * 4 + 2][n] = h * c2;
      h = EXP2F(qb.z * AnE) * h + qb.w * b3; pS[s][half * 4 + 3][n] = h * c3;
    }
    // reduce the 8-step tile: lane sums a quarter-row, 2 shuffles combine
    const float4 a4 = *(const float4*)&pS[s][rrow][qtr * 8];
    const float4 d4 = *(const float4*)&pS[s][rrow][qtr * 8 + 4];
    float sum = ((a4.x + a4.y) + (a4.z + a4.w)) + ((d4.x + d4.y) + (d4.z + d4.w));
    sum += __shfl_xor(sum, 8);
    sum += __shfl_xor(sum, 16);
    if (n < 8) yP[t8 * 8 + n] = sum;
  }
}

// ---------------- K5: merge + Ds-term + out-LN + SiLU(z)* + out_proj + residual ----------------
__global__ __launch_bounds__(256) void k5_merge(
    const float* __restrict__ ys, const float* __restrict__ zb,
    const float* __restrict__ og, const float* __restrict__ ob,
    const float* __restrict__ Wo, const float* __restrict__ resid,
    const float* __restrict__ xc, const float* __restrict__ DsP,
    float* __restrict__ out)
{
  __shared__ float ysS[4][16][128];
  __shared__ float tS[16][128];
  __shared__ float oS[64][17];
  __shared__ float xcS[16][128];
  const int tid = threadIdx.x;
  const int wv = tid >> 6, lane = tid & 63;
  const int pbase = blockIdx.x * 16;
  const int b = pbase / Ll;
  const int lbase = pbase % Ll;
  const int hrow = lbase / Ww, w0 = lbase % Ww;   // 16 | 48 => whole tile in one image row
  {  // stage xc tile + 4-direction ys tiles (ys layout: (b,k,d,l))
    const int dch = tid & 127, seg = tid >> 7;    // seg in {0,1}, 8 l each
    {
      const float4 a4 = *(const float4*)&xc[(b * Dd + dch) * Ll + lbase + seg * 8];
      const float4 c4 = *(const float4*)&xc[(b * Dd + dch) * Ll + lbase + seg * 8 + 4];
      xcS[seg * 8 + 0][dch] = a4.x; xcS[seg * 8 + 1][dch] = a4.y;
      xcS[seg * 8 + 2][dch] = a4.z; xcS[seg * 8 + 3][dch] = a4.w;
      xcS[seg * 8 + 4][dch] = c4.x; xcS[seg * 8 + 5][dch] = c4.y;
      xcS[seg * 8 + 6][dch] = c4.z; xcS[seg * 8 + 7][dch] = c4.w;
    }
    {  // dir 0: contiguous ascending
      const size_t r0 = ((size_t)(b * Kk + 0) * Dd + dch) * Ll + lbase + seg * 8;
      const float4 a4 = *(const float4*)&ys[r0];
      const float4 c4 = *(const float4*)&ys[r0 + 4];
      ysS[0][seg * 8 + 0][dch] = a4.x; ysS[0][seg * 8 + 1][dch] = a4.y;
      ysS[0][seg * 8 + 2][dch] = a4.z; ysS[0][seg * 8 + 3][dch] = a4.w;
      ysS[0][seg * 8 + 4][dch] = c4.x; ysS[0][seg * 8 + 5][dch] = c4.y;
      ysS[0][seg * 8 + 6][dch] = c4.z; ysS[0][seg * 8 + 7][dch] = c4.w;
    }
    {  // dir 2: contiguous, reversed (scan pos L-1-l0)
      const size_t r2 = ((size_t)(b * Kk + 2) * Dd + dch) * Ll + (Ll - 16 - lbase) + seg * 8;
      const float4 a4 = *(const float4*)&ys[r2];
      const float4 c4 = *(const float4*)&ys[r2 + 4];
      ysS[2][15 - seg * 8 - 0][dch] = a4.x; ysS[2][15 - seg * 8 - 1][dch] = a4.y;
      ysS[2][15 - seg * 8 - 2][dch] = a4.z; ysS[2][15 - seg * 8 - 3][dch] = a4.w;
      ysS[2][15 - seg * 8 - 4][dch] = c4.x; ysS[2][15 - seg * 8 - 5][dch] = c4.y;
      ysS[2][15 - seg * 8 - 6][dch] = c4.z; ysS[2][15 - seg * 8 - 7][dch] = c4.w;
    }
    {  // dirs 1,3: scan pos l1 = w*Hh + h (scattered, L2/L3-resident)
      const size_t r1 = ((size_t)(b * Kk + 1) * Dd + dch) * Ll;
      const size_t r3 = ((size_t)(b * Kk + 3) * Dd + dch) * Ll;
      #pragma unroll
      for (int j = 0; j < 8; ++j) {
        const int p = seg * 8 + j;
        const int l1 = (w0 + p) * Hh + hrow;
        ysS[1][p][dch] = ys[r1 + l1];
        ysS[3][p][dch] = ys[r3 + (Ll - 1 - l1)];
      }
    }
  }
  float sDs[2];
  #pragma unroll
  for (int m = 0; m < 2; ++m) {
    const int dch = lane + 64 * m;
    sDs[m] = DsP[dch] + DsP[Dd + dch] + DsP[2 * Dd + dch] + DsP[3 * Dd + dch];
  }
  __syncthreads();
  for (int pi = 0; pi < 4; ++pi) {
    const int p = wv * 4 + pi;
    const int l0 = lbase + p;
    float tv[2];
    #pragma unroll
    for (int m = 0; m < 2; ++m) {
      const int dch = lane + 64 * m;
      tv[m] = ysS[0][p][dch] + ysS[1][p][dch] + ysS[2][p][dch] + ysS[3][p][dch]
            + sDs[m] * xcS[p][dch];
    }
    const float mu = wsum64(tv[0] + tv[1]) * (1.0f / 128.0f);
    const float q = wsum64((tv[0] - mu) * (tv[0] - mu) +
                           (tv[1] - mu) * (tv[1] - mu)) * (1.0f / 128.0f);
    const float rs = rsqrtf(q + EPSf);
    #pragma unroll
    for (int m = 0; m < 2; ++m) {
      const int dch = lane + 64 * m;
      const float zz = zb[(size_t)(b * Ll + l0) * Dd + dch];
      const float sig = 1.0f / (1.0f + __expf(-zz));
      tS[p][dch] = ((tv[m] - mu) * rs * og[dch] + ob[dch]) * (zz * sig);
    }
  }
  __syncthreads();
  float acc[4] = {0.f, 0.f, 0.f, 0.f};
  const float4* W4 = (const float4*)Wo;     // out_proj_w (64,128)
  for (int d4 = 0; d4 < 32; ++d4) {
    const float4 w4 = W4[lane * 32 + d4];
    #pragma unroll
    for (int pi = 0; pi < 4; ++pi) {
      const float4 t4 = ((const float4*)tS[wv * 4 + pi])[d4];
      acc[pi] += t4.x * w4.x + t4.y * w4.y + t4.z * w4.z + t4.w * w4.w;
    }
  }
  #pragma unroll
  for (int pi = 0; pi < 4; ++pi) oS[lane][wv * 4 + pi] = acc[pi];
  __syncthreads();
  const int c = tid >> 2, off = (tid & 3) * 4;
  const size_t obase = (size_t)(b * Cc + c) * Ll + lbase + off;
  const float4 r4 = *(const float4*)(resid + obase);
  float4 o4;
  o4.x = oS[c][off + 0] + r4.x;
  o4.y = oS[c][off + 1] + r4.y;
  o4.z = oS[c][off + 2] + r4.z;
  o4.w = oS[c][off + 3] + r4.w;
  *(float4*)(out + obase) = o4;
}

extern "C" void kernel_launch(void* const* d_in, const int* in_sizes, int n_in,
                              void* d_out, int out_size, void* d_ws, size_t ws_size,
                              hipStream_t stream)
{
  (void)in_sizes; (void)n_in; (void)out_size; (void)ws_size;
  const float* fufea1     = (const float*)d_in[0];
  const float* ln_g       = (const float*)d_in[1];
  const float* ln_b       = (const float*)d_in[2];
  const float* in_proj_w  = (const float*)d_in[3];
  const float* conv_w     = (const float*)d_in[4];
  const float* conv_b     = (const float*)d_in[5];
  const float* x_proj_w   = (const float*)d_in[6];
  const float* dt_w       = (const float*)d_in[7];
  const float* dt_b       = (const float*)d_in[8];
  const float* A_logs     = (const float*)d_in[9];
  const float* Ds         = (const float*)d_in[10];
  const float* out_ln_g   = (const float*)d_in[11];
  const float* out_ln_b   = (const float*)d_in[12];
  const float* out_proj_w = (const float*)d_in[13];

  float* ws  = (float*)d_ws;
  float* zb  = ws;                  // (B,L,D)    589824
  float* xc  = ws + 589824;         // (B,D,L)    589824
  float* ysb = ws + 1179648;        // (B,K,D,L)  2359296
  float* xin = ws + 1179648;        // (B,D,L) — overlaps ysb (dead before k4)
  float* Bm  = ws + 3538944;        // (B,K,L,N)  589824
  float* Cm  = ws + 4128768;        // (B,K,L,N)  589824
  float2* dd2 = (float2*)(ws + 4718592);  // (B,K,D,L) float2 -> 4718592 floats
  // total: 9437184 floats = 37.75 MB

  k1_ln_inproj<<<288, 256, 0, stream>>>(fufea1, ln_g, ln_b, in_proj_w, xin, zb);
  k3_proj<<<576, 512, 0, stream>>>(xin, conv_w, conv_b, x_proj_w, dt_w, dt_b,
                                   xc, dd2, Bm, Cm);
  k4_scan<<<1024, 512, 0, stream>>>(dd2, Bm, Cm, A_logs, ysb);
  k5_merge<<<288, 256, 0, stream>>>(ysb, zb, out_ln_g, out_ln_b, out_proj_w, fufea1,
                                    xc, Ds, (float*)d_out);
}